// Round 1
// baseline (719.726 us; speedup 1.0000x reference)
//
#include <hip/hip_runtime.h>
#include <math.h>

#define Bn 4
#define Cn 96
#define Hn 128
#define Wn 128
#define Ln (Hn*Wn)      // 16384
#define Kn 2
#define Rn 6
#define Sn 64           // scan chunk length
#define NCn (Ln/Sn)     // 256 chunks

__device__ __forceinline__ float siluf(float x) { return x / (1.f + __expf(-x)); }
__device__ __forceinline__ float softplusf(float x) {
    return fmaxf(x, 0.f) + log1pf(__expf(-fabsf(x)));
}

// ---------------------------------------------------------------------------
// Kernel A: in_proj GEMM. x (B,C,L) channel-major -> xc (B,L,C), zs=silu(z) (B,L,C)
// block = 192 threads (one output row each), 64 positions per block staged in LDS.
// ---------------------------------------------------------------------------
__global__ __launch_bounds__(192) void k_inproj(
    const float* __restrict__ x, const float* __restrict__ ipw,
    float* __restrict__ xc, float* __restrict__ zs)
{
    __shared__ float xls[Cn * Sn];      // [c][p] 24 KB
    const int t  = threadIdx.x;
    const int b  = blockIdx.x >> 8;     // 256 tiles per batch
    const int l0 = (blockIdx.x & 255) << 6;

    const float* xp = x + (size_t)b * Cn * Ln + l0;
    for (int idx = t; idx < Cn * Sn; idx += 192) {
        int c = idx >> 6, p = idx & 63;
        xls[idx] = xp[(size_t)c * Ln + p];
    }
    __syncthreads();

    const int o = t;                    // 0..191 output row
    float4 wr[24];
    const float4* wrow = (const float4*)(ipw + o * Cn);
#pragma unroll
    for (int i = 0; i < 24; ++i) wr[i] = wrow[i];

    const bool isz = (o >= Cn);
    float* ob = isz ? (zs + ((size_t)b * Ln + l0) * Cn + (o - Cn))
                    : (xc + ((size_t)b * Ln + l0) * Cn + o);

    for (int pt = 0; pt < 16; ++pt) {
        float4 a = make_float4(0.f, 0.f, 0.f, 0.f);
#pragma unroll
        for (int i = 0; i < 24; ++i) {
            const float4 wv = wr[i];
            float4 xv;
            xv = *(const float4*)&xls[(i*4+0)*Sn + pt*4];
            a.x = fmaf(wv.x, xv.x, a.x); a.y = fmaf(wv.x, xv.y, a.y);
            a.z = fmaf(wv.x, xv.z, a.z); a.w = fmaf(wv.x, xv.w, a.w);
            xv = *(const float4*)&xls[(i*4+1)*Sn + pt*4];
            a.x = fmaf(wv.y, xv.x, a.x); a.y = fmaf(wv.y, xv.y, a.y);
            a.z = fmaf(wv.y, xv.z, a.z); a.w = fmaf(wv.y, xv.w, a.w);
            xv = *(const float4*)&xls[(i*4+2)*Sn + pt*4];
            a.x = fmaf(wv.z, xv.x, a.x); a.y = fmaf(wv.z, xv.y, a.y);
            a.z = fmaf(wv.z, xv.z, a.z); a.w = fmaf(wv.z, xv.w, a.w);
            xv = *(const float4*)&xls[(i*4+3)*Sn + pt*4];
            a.x = fmaf(wv.w, xv.x, a.x); a.y = fmaf(wv.w, xv.y, a.y);
            a.z = fmaf(wv.w, xv.z, a.z); a.w = fmaf(wv.w, xv.w, a.w);
        }
        float v[4] = {a.x, a.y, a.z, a.w};
#pragma unroll
        for (int q = 0; q < 4; ++q) {
            float r = isz ? siluf(v[q]) : v[q];
            ob[(size_t)(pt*4 + q) * Cn] = r;
        }
    }
}

// ---------------------------------------------------------------------------
// Kernel B: depthwise 3x3 conv (SAME, zero pad) + bias + SiLU.
// xc (B,L,C) -> u (B,L,C). One thread per output element, fully coalesced.
// ---------------------------------------------------------------------------
__global__ __launch_bounds__(256) void k_conv(
    const float* __restrict__ xc, const float* __restrict__ cw,
    const float* __restrict__ cb, float* __restrict__ u)
{
    const int e   = blockIdx.x * 256 + threadIdx.x;   // over B*L*C
    const int c   = e % Cn;
    const int pos = e / Cn;                            // b*L + l
    const int l   = pos % Ln;
    const int b   = pos / Ln;
    const int h   = l >> 7, w = l & 127;

    float acc = cb[c];
#pragma unroll
    for (int dh = -1; dh <= 1; ++dh) {
        int hh = h + dh;
        if (hh < 0 || hh >= Hn) continue;
#pragma unroll
        for (int dw = -1; dw <= 1; ++dw) {
            int ww = w + dw;
            if (ww < 0 || ww >= Wn) continue;
            acc = fmaf(cw[c*9 + (dh+1)*3 + (dw+1)],
                       xc[((size_t)b * Ln + (hh << 7) + ww) * Cn + c], acc);
        }
    }
    u[e] = siluf(acc);
}

// ---------------------------------------------------------------------------
// Kernel C: x_dbl projection + delta (softplus) + Bs/Cs extraction.
// Block = (b,k, 64 scan positions). delta stored (B*K, Lscan, C); Bs/Cs (B*K, Lscan).
// ---------------------------------------------------------------------------
__global__ __launch_bounds__(256) void k_xdbl(
    const float* __restrict__ u, const float* __restrict__ xpw,
    const float* __restrict__ dtw, const float* __restrict__ dtb,
    float* __restrict__ delta, float* __restrict__ Bs, float* __restrict__ Cs)
{
    __shared__ float uls[Sn * 97];      // [p][c] padded
    __shared__ float xd[Sn * 8];        // [p][d]
    const int t  = threadIdx.x;
    const int j  = blockIdx.x & 255;
    const int k  = (blockIdx.x >> 8) & 1;
    const int b  = blockIdx.x >> 9;
    const int l0 = j << 6;
    const int bk = b * Kn + k;

    if (k == 0) {
        const float* up = u + ((size_t)b * Ln + l0) * Cn;
        for (int idx = t; idx < Sn * Cn; idx += 256) {
            int p = idx / Cn, c = idx % Cn;
            uls[p * 97 + c] = up[idx];
        }
    } else {
        // scan pos l0+p corresponds to spatial Ln-1-l0-p
        const float* up = u + ((size_t)b * Ln + (Ln - Sn - l0)) * Cn;
        for (int idx = t; idx < Sn * Cn; idx += 256) {
            int p = 63 - idx / Cn, c = idx % Cn;
            uls[p * 97 + c] = up[idx];
        }
    }
    __syncthreads();

    // x_dbl: 8 projections x 64 positions = 512 dot-96 tasks
    for (int dp = t; dp < 512; dp += 256) {
        int d = dp & 7, p = dp >> 3;
        const float* wr = xpw + (k * 8 + d) * Cn;
        float acc = 0.f;
#pragma unroll
        for (int c = 0; c < Cn; ++c) acc = fmaf(wr[c], uls[p * 97 + c], acc);
        xd[p * 8 + d] = acc;
        if (d == 6) Bs[(size_t)bk * Ln + l0 + p] = acc;
        if (d == 7) Cs[(size_t)bk * Ln + l0 + p] = acc;
    }
    __syncthreads();

    float* dout = delta + ((size_t)bk * Ln + l0) * Cn;
    for (int jj = t; jj < Sn * Cn; jj += 256) {
        int c = jj % Cn, p = jj / Cn;
        float acc = dtb[k * Cn + c];
#pragma unroll
        for (int r = 0; r < Rn; ++r)
            acc = fmaf(dtw[(k * Cn + c) * Rn + r], xd[p * 8 + r], acc);
        dout[jj] = softplusf(acc);
    }
}

// ---------------------------------------------------------------------------
// Kernel D: scan phase 1 — per-chunk carry (P = exp(A*sum(delta)), Q = local h).
// block = 192 threads: (2 chunks) x (96 channels) of one (b,k).
// ---------------------------------------------------------------------------
__global__ __launch_bounds__(192) void k_scan1(
    const float* __restrict__ delta, const float* __restrict__ u,
    const float* __restrict__ Bs, const float* __restrict__ Alogs,
    float* __restrict__ Pc, float* __restrict__ Qc)
{
    const int t = threadIdx.x;
    const int c = t % Cn;
    const int ci = t / Cn;                       // 0/1
    const int pair = blockIdx.x & 127;
    const int bk = blockIdx.x >> 7;              // 0..7
    const int k = bk & 1, b = bk >> 1;
    const int chunk = pair * 2 + ci;
    const int ls = chunk * Sn;

    const float Av = -__expf(Alogs[k * Cn + c]);
    const float* dp_ = delta + ((size_t)bk * Ln + ls) * Cn + c;
    const float* Bp  = Bs + (size_t)bk * Ln + ls;

    float h = 0.f, sd = 0.f;
    for (int i = 0; i < Sn; ++i) {
        float de = dp_[(size_t)i * Cn];
        int sp = (k == 0) ? (ls + i) : (Ln - 1 - ls - i);
        float xv = u[((size_t)b * Ln + sp) * Cn + c];
        float dA = __expf(de * Av);
        h = fmaf(dA, h, de * xv * Bp[i]);
        sd += de;
    }
    Pc[((size_t)bk * NCn + chunk) * Cn + c] = __expf(Av * sd);
    Qc[((size_t)bk * NCn + chunk) * Cn + c] = h;
}

// ---------------------------------------------------------------------------
// Kernel E: scan phase 2 — sequential carry combine over 256 chunks, 768 series.
// ---------------------------------------------------------------------------
__global__ __launch_bounds__(256) void k_scan2(
    const float* __restrict__ Pc, const float* __restrict__ Qc,
    float* __restrict__ hinit)
{
    const int tg = blockIdx.x * 256 + threadIdx.x;   // 0..767
    const int c = tg % Cn, bk = tg / Cn;
    float h = 0.f;
    for (int j = 0; j < NCn; ++j) {
        size_t idx = ((size_t)bk * NCn + j) * Cn + c;
        hinit[idx] = h;
        h = fmaf(Pc[idx], h, Qc[idx]);
    }
}

// ---------------------------------------------------------------------------
// Kernel F: scan phase 3 + full epilogue.
// Block = (b, spatial tile j of 64): runs k=0 chunk j and k=1 chunk NCn-1-j
// (same spatial range), combines + D*xs, LayerNorm over C, gate silu(z),
// out_proj 96x96 matvec, scale_w. Writes final out (B,C,L).
// ---------------------------------------------------------------------------
__global__ __launch_bounds__(256) void k_scan3(
    const float* __restrict__ delta, const float* __restrict__ u,
    const float* __restrict__ Bs, const float* __restrict__ Cs,
    const float* __restrict__ hinit, const float* __restrict__ Alogs,
    const float* __restrict__ Ds, const float* __restrict__ onw,
    const float* __restrict__ onb, const float* __restrict__ zs,
    const float* __restrict__ opw, const float* __restrict__ scw,
    float* __restrict__ out)
{
    __shared__ float y0[Sn * 97];
    __shared__ float y1[Sn * 97];
    __shared__ float mu[Sn], isd[Sn];
    const int t = threadIdx.x;
    const int j = blockIdx.x & 255;
    const int b = blockIdx.x >> 8;
    const int l0 = j << 6;

    if (t < 192) {
        const int k = t / Cn, c = t % Cn;
        const int bk = b * Kn + k;
        const int chunk = (k == 0) ? j : (NCn - 1 - j);
        const int ls = chunk * Sn;
        float h = hinit[((size_t)bk * NCn + chunk) * Cn + c];
        const float Av = -__expf(Alogs[k * Cn + c]);
        const float* dp_ = delta + ((size_t)bk * Ln + ls) * Cn + c;
        const float* Bp = Bs + (size_t)bk * Ln + ls;
        const float* Cp = Cs + (size_t)bk * Ln + ls;
        float* ytile = (k == 0) ? y0 : y1;
        for (int i = 0; i < Sn; ++i) {
            float de = dp_[(size_t)i * Cn];
            int sp = (k == 0) ? (ls + i) : (Ln - 1 - ls - i);
            float xv = u[((size_t)b * Ln + sp) * Cn + c];
            float dA = __expf(de * Av);
            h = fmaf(dA, h, de * xv * Bp[i]);
            float yv = h * Cp[i];
            int row = (k == 0) ? i : (Sn - 1 - i);
            ytile[row * 97 + c] = yv;
        }
    }
    __syncthreads();

    // combine both directions + D*xs
    const float* ub = u + ((size_t)b * Ln + l0) * Cn;
    for (int jj = t; jj < Sn * Cn; jj += 256) {
        int c = jj % Cn, p = jj / Cn;
        float yc = y0[p * 97 + c] + y1[p * 97 + c] + (Ds[c] + Ds[Cn + c]) * ub[jj];
        y0[p * 97 + c] = yc;
    }
    __syncthreads();

    // LayerNorm stats per position (over 96 channels)
    if (t < Sn) {
        float s = 0.f, ss = 0.f;
#pragma unroll
        for (int c = 0; c < Cn; ++c) { float v = y0[t * 97 + c]; s += v; ss += v * v; }
        float m = s * (1.f / Cn);
        float var = ss * (1.f / Cn) - m * m;
        mu[t] = m;
        isd[t] = rsqrtf(var + 1e-5f);
    }
    __syncthreads();

    // normalize + affine + gate with silu(z)
    const float* zb = zs + ((size_t)b * Ln + l0) * Cn;
    for (int jj = t; jj < Sn * Cn; jj += 256) {
        int c = jj % Cn, p = jj / Cn;
        float v = (y0[p * 97 + c] - mu[p]) * isd[p] * onw[c] + onb[c];
        y0[p * 97 + c] = v * zb[jj];
    }
    __syncthreads();

    // out_proj: out[b,o,l] = scw[o] * sum_c opw[o,c]*g[p,c]
    for (int jj = t; jj < Cn * Sn; jj += 256) {
        int pos = jj & 63, o = jj >> 6;
        const float* wr = opw + o * Cn;
        float acc = 0.f;
#pragma unroll
        for (int c = 0; c < Cn; ++c) acc = fmaf(wr[c], y0[pos * 97 + c], acc);
        out[((size_t)b * Cn + o) * Ln + l0 + pos] = acc * scw[o];
    }
}

// ---------------------------------------------------------------------------
extern "C" void kernel_launch(void* const* d_in, const int* in_sizes, int n_in,
                              void* d_out, int out_size, void* d_ws, size_t ws_size,
                              hipStream_t stream)
{
    const float* x     = (const float*)d_in[0];
    const float* ipw   = (const float*)d_in[1];
    const float* cw    = (const float*)d_in[2];
    const float* cb    = (const float*)d_in[3];
    const float* xpw   = (const float*)d_in[4];
    const float* dtw   = (const float*)d_in[5];
    const float* dtb   = (const float*)d_in[6];
    const float* Alogs = (const float*)d_in[7];
    const float* Ds    = (const float*)d_in[8];
    const float* onw   = (const float*)d_in[9];
    const float* onb   = (const float*)d_in[10];
    const float* opw   = (const float*)d_in[11];
    const float* scw   = (const float*)d_in[12];
    float* out = (float*)d_out;

    float* wsp = (float*)d_ws;
    size_t off = 0;
    float* xc    = wsp + off; off += (size_t)Bn * Ln * Cn;        // 6.29M
    float* zs    = wsp + off; off += (size_t)Bn * Ln * Cn;        // 6.29M
    float* u     = wsp + off; off += (size_t)Bn * Ln * Cn;        // 6.29M
    float* delta = wsp + off; off += (size_t)Bn * Kn * Ln * Cn;   // 12.58M
    float* Bsb   = wsp + off; off += (size_t)Bn * Kn * Ln;
    float* Csb   = wsp + off; off += (size_t)Bn * Kn * Ln;
    float* Pc    = wsp + off; off += (size_t)Bn * Kn * NCn * Cn;
    float* Qc    = wsp + off; off += (size_t)Bn * Kn * NCn * Cn;
    float* hinit = wsp + off; off += (size_t)Bn * Kn * NCn * Cn;
    // total ~32.3M floats = ~129 MB of workspace

    k_inproj<<<Bn * (Ln / Sn), 192, 0, stream>>>(x, ipw, xc, zs);
    k_conv  <<<(Bn * Ln * Cn) / 256, 256, 0, stream>>>(xc, cw, cb, u);
    k_xdbl  <<<Bn * Kn * (Ln / Sn), 256, 0, stream>>>(u, xpw, dtw, dtb, delta, Bsb, Csb);
    k_scan1 <<<Bn * Kn * (NCn / 2), 192, 0, stream>>>(delta, u, Bsb, Alogs, Pc, Qc);
    k_scan2 <<<3, 256, 0, stream>>>(Pc, Qc, hinit);
    k_scan3 <<<Bn * (Ln / Sn), 256, 0, stream>>>(delta, u, Bsb, Csb, hinit, Alogs,
                                                 Ds, onw, onb, zs, opw, scw, out);
}

// Round 2
// 521.838 us; speedup vs baseline: 1.3792x; 1.3792x over previous
//
#include <hip/hip_runtime.h>
#include <math.h>

#define Bn 4
#define Cn 96
#define Hn 128
#define Wn 128
#define Ln (Hn*Wn)      // 16384
#define Kn 2
#define Rn 6
#define Sn 64           // scan chunk length
#define NCn (Ln/Sn)     // 256 chunks

__device__ __forceinline__ float siluf(float x) { return x / (1.f + __expf(-x)); }
__device__ __forceinline__ float softplusf(float x) {
    return fmaxf(x, 0.f) + log1pf(__expf(-fabsf(x)));
}

// ---------------------------------------------------------------------------
// Kernel A: in_proj GEMM. x (B,C,L) -> xc (B,L,C), zs=silu(z) (B,L,C).
// Register-blocked: block = 256 thr, tile 64 pos x 192 out, thread = 4 pos x 12 out.
// K chunked by 32 through LDS. 33KB LDS -> 4 blocks/CU; VGPR capped at 128.
// ---------------------------------------------------------------------------
__global__ __launch_bounds__(256, 4) void k_inproj(
    const float* __restrict__ x, const float* __restrict__ ipw,
    float* __restrict__ xc, float* __restrict__ zs)
{
    __shared__ float xls[32 * 64];       // [k][p]  8 KB
    __shared__ float wls[32 * 196];      // [k][o]  25 KB (pad 196: 16B-aligned rows)
    const int t  = threadIdx.x;
    const int b  = blockIdx.x >> 8;
    const int l0 = (blockIdx.x & 255) << 6;
    const int tx = t & 15;               // position group: p = tx*4 .. tx*4+3
    const int ty = t >> 4;               // output group:   o = ty*12 .. ty*12+11

    float acc[12][4];
#pragma unroll
    for (int i = 0; i < 12; ++i)
#pragma unroll
        for (int j = 0; j < 4; ++j) acc[i][j] = 0.f;

    const float* xbase = x + (size_t)b * Cn * Ln + l0;

    for (int k0 = 0; k0 < Cn; k0 += 32) {
        if (k0) __syncthreads();
        // x chunk: 32x64 floats = 512 float4, 2 per thread, coalesced
        {
            int idx = t;
#pragma unroll
            for (int q = 0; q < 2; ++q, idx += 256) {
                int k = idx >> 4, p4 = idx & 15;
                *(float4*)&xls[k * 64 + p4 * 4] =
                    *(const float4*)&xbase[(size_t)(k0 + k) * Ln + p4 * 4];
            }
        }
        // w chunk: 32x192 floats, 24 per thread; LDS writes bank-sequential
        for (int idx = t; idx < 32 * 192; idx += 256) {
            int o = idx % 192, k = idx / 192;
            wls[k * 196 + o] = ipw[o * Cn + k0 + k];
        }
        __syncthreads();

#pragma unroll 4
        for (int kk = 0; kk < 32; ++kk) {
            float4 xv = *(const float4*)&xls[kk * 64 + tx * 4];
            const float* wrow = &wls[kk * 196 + ty * 12];
            float4 w0 = *(const float4*)&wrow[0];
            float4 w1 = *(const float4*)&wrow[4];
            float4 w2 = *(const float4*)&wrow[8];
            float wv[12] = {w0.x,w0.y,w0.z,w0.w,w1.x,w1.y,w1.z,w1.w,w2.x,w2.y,w2.z,w2.w};
            float xa[4]  = {xv.x, xv.y, xv.z, xv.w};
#pragma unroll
            for (int i = 0; i < 12; ++i)
#pragma unroll
                for (int j = 0; j < 4; ++j)
                    acc[i][j] = fmaf(wv[i], xa[j], acc[i][j]);
        }
    }

    // epilogue: o = ty*12+i ; ty<8 -> xc, ty>=8 -> zs (wave-uniform branch)
    const size_t posbase = (size_t)b * Ln + l0 + tx * 4;
#pragma unroll
    for (int i = 0; i < 12; ++i) {
        const int o = ty * 12 + i;
        const bool isz = (o >= Cn);
        float* ob = isz ? (zs + posbase * Cn + (o - Cn)) : (xc + posbase * Cn + o);
#pragma unroll
        for (int j = 0; j < 4; ++j) {
            float v = acc[i][j];
            if (isz) v = siluf(v);
            ob[(size_t)j * Cn] = v;
        }
    }
}

// ---------------------------------------------------------------------------
// Kernel B: depthwise 3x3 conv (SAME, zero pad) + bias + SiLU.
// xc (B,L,C) -> u (B,L,C). One thread per output element, fully coalesced.
// ---------------------------------------------------------------------------
__global__ __launch_bounds__(256) void k_conv(
    const float* __restrict__ xc, const float* __restrict__ cw,
    const float* __restrict__ cb, float* __restrict__ u)
{
    const int e   = blockIdx.x * 256 + threadIdx.x;   // over B*L*C
    const int c   = e % Cn;
    const int pos = e / Cn;                            // b*L + l
    const int l   = pos % Ln;
    const int b   = pos / Ln;
    const int h   = l >> 7, w = l & 127;

    float acc = cb[c];
#pragma unroll
    for (int dh = -1; dh <= 1; ++dh) {
        int hh = h + dh;
        if (hh < 0 || hh >= Hn) continue;
#pragma unroll
        for (int dw = -1; dw <= 1; ++dw) {
            int ww = w + dw;
            if (ww < 0 || ww >= Wn) continue;
            acc = fmaf(cw[c*9 + (dh+1)*3 + (dw+1)],
                       xc[((size_t)b * Ln + (hh << 7) + ww) * Cn + c], acc);
        }
    }
    u[e] = siluf(acc);
}

// ---------------------------------------------------------------------------
// Kernel C: x_dbl projection + delta (softplus) + Bs/Cs extraction.
// Block = (b,k, 64 scan positions). delta stored (B*K, Lscan, C); Bs/Cs (B*K, Lscan).
// ---------------------------------------------------------------------------
__global__ __launch_bounds__(256) void k_xdbl(
    const float* __restrict__ u, const float* __restrict__ xpw,
    const float* __restrict__ dtw, const float* __restrict__ dtb,
    float* __restrict__ delta, float* __restrict__ Bs, float* __restrict__ Cs)
{
    __shared__ float uls[Sn * 97];      // [p][c] padded
    __shared__ float xd[Sn * 8];        // [p][d]
    const int t  = threadIdx.x;
    const int j  = blockIdx.x & 255;
    const int k  = (blockIdx.x >> 8) & 1;
    const int b  = blockIdx.x >> 9;
    const int l0 = j << 6;
    const int bk = b * Kn + k;

    if (k == 0) {
        const float* up = u + ((size_t)b * Ln + l0) * Cn;
        for (int idx = t; idx < Sn * Cn; idx += 256) {
            int p = idx / Cn, c = idx % Cn;
            uls[p * 97 + c] = up[idx];
        }
    } else {
        // scan pos l0+p corresponds to spatial Ln-1-l0-p
        const float* up = u + ((size_t)b * Ln + (Ln - Sn - l0)) * Cn;
        for (int idx = t; idx < Sn * Cn; idx += 256) {
            int p = 63 - idx / Cn, c = idx % Cn;
            uls[p * 97 + c] = up[idx];
        }
    }
    __syncthreads();

    // x_dbl: 8 projections x 64 positions = 512 dot-96 tasks
    for (int dp = t; dp < 512; dp += 256) {
        int d = dp & 7, p = dp >> 3;
        const float* wr = xpw + (k * 8 + d) * Cn;
        float acc = 0.f;
#pragma unroll
        for (int c = 0; c < Cn; ++c) acc = fmaf(wr[c], uls[p * 97 + c], acc);
        xd[p * 8 + d] = acc;
        if (d == 6) Bs[(size_t)bk * Ln + l0 + p] = acc;
        if (d == 7) Cs[(size_t)bk * Ln + l0 + p] = acc;
    }
    __syncthreads();

    float* dout = delta + ((size_t)bk * Ln + l0) * Cn;
    for (int jj = t; jj < Sn * Cn; jj += 256) {
        int c = jj % Cn, p = jj / Cn;
        float acc = dtb[k * Cn + c];
#pragma unroll
        for (int r = 0; r < Rn; ++r)
            acc = fmaf(dtw[(k * Cn + c) * Rn + r], xd[p * 8 + r], acc);
        dout[jj] = softplusf(acc);
    }
}

// ---------------------------------------------------------------------------
// Kernel D: scan phase 1 — per-chunk carry (P = exp(A*sum(delta)), Q = local h).
// block = 192 threads: (2 chunks) x (96 channels) of one (b,k).
// ---------------------------------------------------------------------------
__global__ __launch_bounds__(192) void k_scan1(
    const float* __restrict__ delta, const float* __restrict__ u,
    const float* __restrict__ Bs, const float* __restrict__ Alogs,
    float* __restrict__ Pc, float* __restrict__ Qc)
{
    const int t = threadIdx.x;
    const int c = t % Cn;
    const int ci = t / Cn;                       // 0/1
    const int pair = blockIdx.x & 127;
    const int bk = blockIdx.x >> 7;              // 0..7
    const int k = bk & 1, b = bk >> 1;
    const int chunk = pair * 2 + ci;
    const int ls = chunk * Sn;

    const float Av = -__expf(Alogs[k * Cn + c]);
    const float* dp_ = delta + ((size_t)bk * Ln + ls) * Cn + c;
    const float* Bp  = Bs + (size_t)bk * Ln + ls;

    float h = 0.f, sd = 0.f;
    for (int i = 0; i < Sn; ++i) {
        float de = dp_[(size_t)i * Cn];
        int sp = (k == 0) ? (ls + i) : (Ln - 1 - ls - i);
        float xv = u[((size_t)b * Ln + sp) * Cn + c];
        float dA = __expf(de * Av);
        h = fmaf(dA, h, de * xv * Bp[i]);
        sd += de;
    }
    Pc[((size_t)bk * NCn + chunk) * Cn + c] = __expf(Av * sd);
    Qc[((size_t)bk * NCn + chunk) * Cn + c] = h;
}

// ---------------------------------------------------------------------------
// Kernel E: scan phase 2 — sequential carry combine over 256 chunks, 768 series.
// ---------------------------------------------------------------------------
__global__ __launch_bounds__(256) void k_scan2(
    const float* __restrict__ Pc, const float* __restrict__ Qc,
    float* __restrict__ hinit)
{
    const int tg = blockIdx.x * 256 + threadIdx.x;   // 0..767
    const int c = tg % Cn, bk = tg / Cn;
    float h = 0.f;
    for (int j = 0; j < NCn; ++j) {
        size_t idx = ((size_t)bk * NCn + j) * Cn + c;
        hinit[idx] = h;
        h = fmaf(Pc[idx], h, Qc[idx]);
    }
}

// ---------------------------------------------------------------------------
// Kernel F: scan phase 3 + full epilogue.
// Block = (b, spatial tile j of 64): runs k=0 chunk j and k=1 chunk NCn-1-j
// (same spatial range), combines + D*xs, LayerNorm over C, gate silu(z),
// out_proj 96x96 matvec, scale_w. Writes final out (B,C,L).
// ---------------------------------------------------------------------------
__global__ __launch_bounds__(256) void k_scan3(
    const float* __restrict__ delta, const float* __restrict__ u,
    const float* __restrict__ Bs, const float* __restrict__ Cs,
    const float* __restrict__ hinit, const float* __restrict__ Alogs,
    const float* __restrict__ Ds, const float* __restrict__ onw,
    const float* __restrict__ onb, const float* __restrict__ zs,
    const float* __restrict__ opw, const float* __restrict__ scw,
    float* __restrict__ out)
{
    __shared__ float y0[Sn * 97];
    __shared__ float y1[Sn * 97];
    __shared__ float mu[Sn], isd[Sn];
    const int t = threadIdx.x;
    const int j = blockIdx.x & 255;
    const int b = blockIdx.x >> 8;
    const int l0 = j << 6;

    if (t < 192) {
        const int k = t / Cn, c = t % Cn;
        const int bk = b * Kn + k;
        const int chunk = (k == 0) ? j : (NCn - 1 - j);
        const int ls = chunk * Sn;
        float h = hinit[((size_t)bk * NCn + chunk) * Cn + c];
        const float Av = -__expf(Alogs[k * Cn + c]);
        const float* dp_ = delta + ((size_t)bk * Ln + ls) * Cn + c;
        const float* Bp = Bs + (size_t)bk * Ln + ls;
        const float* Cp = Cs + (size_t)bk * Ln + ls;
        float* ytile = (k == 0) ? y0 : y1;
        for (int i = 0; i < Sn; ++i) {
            float de = dp_[(size_t)i * Cn];
            int sp = (k == 0) ? (ls + i) : (Ln - 1 - ls - i);
            float xv = u[((size_t)b * Ln + sp) * Cn + c];
            float dA = __expf(de * Av);
            h = fmaf(dA, h, de * xv * Bp[i]);
            float yv = h * Cp[i];
            int row = (k == 0) ? i : (Sn - 1 - i);
            ytile[row * 97 + c] = yv;
        }
    }
    __syncthreads();

    // combine both directions + D*xs
    const float* ub = u + ((size_t)b * Ln + l0) * Cn;
    for (int jj = t; jj < Sn * Cn; jj += 256) {
        int c = jj % Cn, p = jj / Cn;
        float yc = y0[p * 97 + c] + y1[p * 97 + c] + (Ds[c] + Ds[Cn + c]) * ub[jj];
        y0[p * 97 + c] = yc;
    }
    __syncthreads();

    // LayerNorm stats per position (over 96 channels)
    if (t < Sn) {
        float s = 0.f, ss = 0.f;
#pragma unroll
        for (int c = 0; c < Cn; ++c) { float v = y0[t * 97 + c]; s += v; ss += v * v; }
        float m = s * (1.f / Cn);
        float var = ss * (1.f / Cn) - m * m;
        mu[t] = m;
        isd[t] = rsqrtf(var + 1e-5f);
    }
    __syncthreads();

    // normalize + affine + gate with silu(z)
    const float* zb = zs + ((size_t)b * Ln + l0) * Cn;
    for (int jj = t; jj < Sn * Cn; jj += 256) {
        int c = jj % Cn, p = jj / Cn;
        float v = (y0[p * 97 + c] - mu[p]) * isd[p] * onw[c] + onb[c];
        y0[p * 97 + c] = v * zb[jj];
    }
    __syncthreads();

    // out_proj: out[b,o,l] = scw[o] * sum_c opw[o,c]*g[p,c]
    for (int jj = t; jj < Cn * Sn; jj += 256) {
        int pos = jj & 63, o = jj >> 6;
        const float* wr = opw + o * Cn;
        float acc = 0.f;
#pragma unroll
        for (int c = 0; c < Cn; ++c) acc = fmaf(wr[c], y0[pos * 97 + c], acc);
        out[((size_t)b * Cn + o) * Ln + l0 + pos] = acc * scw[o];
    }
}

// ---------------------------------------------------------------------------
extern "C" void kernel_launch(void* const* d_in, const int* in_sizes, int n_in,
                              void* d_out, int out_size, void* d_ws, size_t ws_size,
                              hipStream_t stream)
{
    const float* x     = (const float*)d_in[0];
    const float* ipw   = (const float*)d_in[1];
    const float* cw    = (const float*)d_in[2];
    const float* cb    = (const float*)d_in[3];
    const float* xpw   = (const float*)d_in[4];
    const float* dtw   = (const float*)d_in[5];
    const float* dtb   = (const float*)d_in[6];
    const float* Alogs = (const float*)d_in[7];
    const float* Ds    = (const float*)d_in[8];
    const float* onw   = (const float*)d_in[9];
    const float* onb   = (const float*)d_in[10];
    const float* opw   = (const float*)d_in[11];
    const float* scw   = (const float*)d_in[12];
    float* out = (float*)d_out;

    float* wsp = (float*)d_ws;
    size_t off = 0;
    float* xc    = wsp + off; off += (size_t)Bn * Ln * Cn;        // 6.29M
    float* zs    = wsp + off; off += (size_t)Bn * Ln * Cn;        // 6.29M
    float* u     = wsp + off; off += (size_t)Bn * Ln * Cn;        // 6.29M
    float* delta = wsp + off; off += (size_t)Bn * Kn * Ln * Cn;   // 12.58M
    float* Bsb   = wsp + off; off += (size_t)Bn * Kn * Ln;
    float* Csb   = wsp + off; off += (size_t)Bn * Kn * Ln;
    float* Pc    = wsp + off; off += (size_t)Bn * Kn * NCn * Cn;
    float* Qc    = wsp + off; off += (size_t)Bn * Kn * NCn * Cn;
    float* hinit = wsp + off; off += (size_t)Bn * Kn * NCn * Cn;
    // total ~32.3M floats = ~129 MB of workspace

    k_inproj<<<Bn * (Ln / Sn), 256, 0, stream>>>(x, ipw, xc, zs);
    k_conv  <<<(Bn * Ln * Cn) / 256, 256, 0, stream>>>(xc, cw, cb, u);
    k_xdbl  <<<Bn * Kn * (Ln / Sn), 256, 0, stream>>>(u, xpw, dtw, dtb, delta, Bsb, Csb);
    k_scan1 <<<Bn * Kn * (NCn / 2), 192, 0, stream>>>(delta, u, Bsb, Alogs, Pc, Qc);
    k_scan2 <<<3, 256, 0, stream>>>(Pc, Qc, hinit);
    k_scan3 <<<Bn * (Ln / Sn), 256, 0, stream>>>(delta, u, Bsb, Csb, hinit, Alogs,
                                                 Ds, onw, onb, zs, opw, scw, out);
}

// Round 3
// 440.066 us; speedup vs baseline: 1.6355x; 1.1858x over previous
//
#include <hip/hip_runtime.h>
#include <math.h>

#define Bn 4
#define Cn 96
#define Hn 128
#define Wn 128
#define Ln (Hn*Wn)      // 16384
#define Kn 2
#define Rn 6
#define SC 32           // scan chunk length
#define NCH (Ln/SC)     // 512 chunks per (b,k)

__device__ __forceinline__ float siluf(float x) { return x / (1.f + __expf(-x)); }
__device__ __forceinline__ float softplusf(float x) {
    return fmaxf(x, 0.f) + log1pf(__expf(-fabsf(x)));
}

// ---------------------------------------------------------------------------
// Kernel A: in_proj GEMM. x (B,C,L) -> xc (B,L,C), zs=silu(z) (B,L,C).
// Register-blocked: block = 256 thr, tile 64 pos x 192 out, thread = 4 pos x 12 out.
// ---------------------------------------------------------------------------
__global__ __launch_bounds__(256, 4) void k_inproj(
    const float* __restrict__ x, const float* __restrict__ ipw,
    float* __restrict__ xc, float* __restrict__ zs)
{
    __shared__ float xls[32 * 64];       // [k][p]  8 KB
    __shared__ float wls[32 * 196];      // [k][o]  25 KB
    const int t  = threadIdx.x;
    const int b  = blockIdx.x >> 8;
    const int l0 = (blockIdx.x & 255) << 6;
    const int tx = t & 15;
    const int ty = t >> 4;

    float acc[12][4];
#pragma unroll
    for (int i = 0; i < 12; ++i)
#pragma unroll
        for (int j = 0; j < 4; ++j) acc[i][j] = 0.f;

    const float* xbase = x + (size_t)b * Cn * Ln + l0;

    for (int k0 = 0; k0 < Cn; k0 += 32) {
        if (k0) __syncthreads();
        {
            int idx = t;
#pragma unroll
            for (int q = 0; q < 2; ++q, idx += 256) {
                int k = idx >> 4, p4 = idx & 15;
                *(float4*)&xls[k * 64 + p4 * 4] =
                    *(const float4*)&xbase[(size_t)(k0 + k) * Ln + p4 * 4];
            }
        }
        for (int idx = t; idx < 32 * 192; idx += 256) {
            int o = idx % 192, k = idx / 192;
            wls[k * 196 + o] = ipw[o * Cn + k0 + k];
        }
        __syncthreads();

#pragma unroll 4
        for (int kk = 0; kk < 32; ++kk) {
            float4 xv = *(const float4*)&xls[kk * 64 + tx * 4];
            const float* wrow = &wls[kk * 196 + ty * 12];
            float4 w0 = *(const float4*)&wrow[0];
            float4 w1 = *(const float4*)&wrow[4];
            float4 w2 = *(const float4*)&wrow[8];
            float wv[12] = {w0.x,w0.y,w0.z,w0.w,w1.x,w1.y,w1.z,w1.w,w2.x,w2.y,w2.z,w2.w};
            float xa[4]  = {xv.x, xv.y, xv.z, xv.w};
#pragma unroll
            for (int i = 0; i < 12; ++i)
#pragma unroll
                for (int j = 0; j < 4; ++j)
                    acc[i][j] = fmaf(wv[i], xa[j], acc[i][j]);
        }
    }

    const size_t posbase = (size_t)b * Ln + l0 + tx * 4;
#pragma unroll
    for (int i = 0; i < 12; ++i) {
        const int o = ty * 12 + i;
        const bool isz = (o >= Cn);
        float* ob = isz ? (zs + posbase * Cn + (o - Cn)) : (xc + posbase * Cn + o);
#pragma unroll
        for (int j = 0; j < 4; ++j) {
            float v = acc[i][j];
            if (isz) v = siluf(v);
            ob[(size_t)j * Cn] = v;
        }
    }
}

// ---------------------------------------------------------------------------
// Kernel B: depthwise 3x3 conv (SAME) + bias + SiLU.  xc (B,L,C) -> u (B,L,C).
// ---------------------------------------------------------------------------
__global__ __launch_bounds__(256) void k_conv(
    const float* __restrict__ xc, const float* __restrict__ cw,
    const float* __restrict__ cb, float* __restrict__ u)
{
    const int e   = blockIdx.x * 256 + threadIdx.x;
    const int c   = e % Cn;
    const int pos = e / Cn;
    const int l   = pos % Ln;
    const int b   = pos / Ln;
    const int h   = l >> 7, w = l & 127;

    float acc = cb[c];
#pragma unroll
    for (int dh = -1; dh <= 1; ++dh) {
        int hh = h + dh;
        if (hh < 0 || hh >= Hn) continue;
#pragma unroll
        for (int dw = -1; dw <= 1; ++dw) {
            int ww = w + dw;
            if (ww < 0 || ww >= Wn) continue;
            acc = fmaf(cw[c*9 + (dh+1)*3 + (dw+1)],
                       xc[((size_t)b * Ln + (hh << 7) + ww) * Cn + c], acc);
        }
    }
    u[e] = siluf(acc);
}

// ---------------------------------------------------------------------------
// Kernel C: fused x_dbl + delta + local scan.
// Block = (b,k, 64 scan positions = 2 chunks of 32), 192 threads.
// Stages u tile in LDS, computes xd (8 proj/pos) in LDS, then each thread
// (c, chunk) runs the 32-step local recurrence computing delta on the fly.
// Stores yloc = h_local*C and cp = cumP*C per position; (P,Q) carry per chunk.
// ---------------------------------------------------------------------------
__global__ __launch_bounds__(192) void k_fscan1(
    const float* __restrict__ u, const float* __restrict__ xpw,
    const float* __restrict__ dtw, const float* __restrict__ dtb,
    const float* __restrict__ Alogs,
    float* __restrict__ yloc, float* __restrict__ cpb,
    float* __restrict__ Pc, float* __restrict__ Qc)
{
    __shared__ float uls[64 * 97];   // [p][c] padded
    __shared__ float xd[64 * 8];     // [p][d]
    const int t   = threadIdx.x;
    const int seg = blockIdx.x & 255;
    const int k   = (blockIdx.x >> 8) & 1;
    const int b   = blockIdx.x >> 9;
    const int bk  = b * Kn + k;
    const int l0  = seg << 6;        // scan-position base (64 positions)

    if (k == 0) {
        const float* up = u + ((size_t)b * Ln + l0) * Cn;
        for (int idx = t; idx < 64 * Cn; idx += 192) {
            int p = idx / Cn, c = idx % Cn;
            uls[p * 97 + c] = up[idx];
        }
    } else {
        const float* up = u + ((size_t)b * Ln + (Ln - 64 - l0)) * Cn;
        for (int idx = t; idx < 64 * Cn; idx += 192) {
            int p = 63 - idx / Cn, c = idx % Cn;
            uls[p * 97 + c] = up[idx];
        }
    }
    __syncthreads();

    for (int dp = t; dp < 512; dp += 192) {
        int d = dp & 7, p = dp >> 3;
        const float* wr = xpw + (k * 8 + d) * Cn;
        float acc = 0.f;
#pragma unroll
        for (int c = 0; c < Cn; ++c) acc = fmaf(wr[c], uls[p * 97 + c], acc);
        xd[p * 8 + d] = acc;
    }
    __syncthreads();

    const int c  = t % Cn;
    const int ci = t / Cn;           // chunk within tile: 0/1
    const int pbase = ci * SC;
    const float Av = -__expf(Alogs[k * Cn + c]);
    const float bias = dtb[k * Cn + c];
    float dtwr[Rn];
#pragma unroll
    for (int r = 0; r < Rn; ++r) dtwr[r] = dtw[(k * Cn + c) * Rn + r];

    float h = 0.f, sd = 0.f, cp = 1.f;
    const size_t gbase = ((size_t)bk * Ln + l0 + pbase) * Cn + c;
    for (int i = 0; i < SC; ++i) {
        const float* xr = &xd[(pbase + i) * 8];
        float de = bias;
#pragma unroll
        for (int r = 0; r < Rn; ++r) de = fmaf(dtwr[r], xr[r], de);
        de = softplusf(de);
        float dA = __expf(de * Av);
        float xv = uls[(pbase + i) * 97 + c];
        h = fmaf(dA, h, de * xv * xr[6]);
        sd += de;
        cp = __expf(Av * sd);
        yloc[gbase + (size_t)i * Cn] = h * xr[7];
        cpb [gbase + (size_t)i * Cn] = cp * xr[7];
    }
    const size_t cidx = ((size_t)bk * NCH + seg * 2 + ci) * Cn + c;
    Pc[cidx] = cp;
    Qc[cidx] = h;
}

// ---------------------------------------------------------------------------
// Kernel D: hierarchical carry scan. 768 series x 512 chunks.
// Grid = 24 blocks (8 bk x 3 channel-slices of 32), block = 1024 thr (32c x 32g),
// group = 16 chunks. Phase1: per-group carry (16 steps). Phase2: 32-step serial
// over groups (32 threads). Phase3: replay within group writing hinit.
// ---------------------------------------------------------------------------
__global__ __launch_bounds__(1024) void k_scan2(
    const float* __restrict__ Pc, const float* __restrict__ Qc,
    float* __restrict__ hinit)
{
    __shared__ float Pg[32][33], Qg[32][33], gini[32][33];
    const int bk    = blockIdx.x / 3;
    const int cbase = (blockIdx.x % 3) * 32;
    const int t = threadIdx.x;
    const int c = t & 31, g = t >> 5;

    const size_t base = ((size_t)bk * NCH + g * 16) * Cn + cbase + c;
    float P = 1.f, Q = 0.f;
    for (int j = 0; j < 16; ++j) {
        size_t idx = base + (size_t)j * Cn;
        float p_ = Pc[idx], q_ = Qc[idx];
        Q = fmaf(p_, Q, q_);
        P *= p_;
    }
    Pg[g][c] = P; Qg[g][c] = Q;
    __syncthreads();
    if (t < 32) {
        float h = 0.f;
        for (int gg = 0; gg < 32; ++gg) {
            gini[gg][t] = h;
            h = fmaf(Pg[gg][t], h, Qg[gg][t]);
        }
    }
    __syncthreads();
    float h = gini[g][c];
    for (int j = 0; j < 16; ++j) {
        size_t idx = base + (size_t)j * Cn;
        hinit[idx] = h;
        h = fmaf(Pc[idx], h, Qc[idx]);
    }
}

// ---------------------------------------------------------------------------
// Kernel E: correction + epilogue (no serial phase).
// Block = (b, 64-position spatial tile): y = yloc0+cp0*h0 + yloc1+cp1*h1 + D*u,
// LayerNorm over C, gate silu(z), out_proj 96x96, scale. Writes out (B,C,L).
// ---------------------------------------------------------------------------
__global__ __launch_bounds__(256) void k_scan3(
    const float* __restrict__ yloc, const float* __restrict__ cpb,
    const float* __restrict__ hinit, const float* __restrict__ u,
    const float* __restrict__ Ds, const float* __restrict__ onw,
    const float* __restrict__ onb, const float* __restrict__ zs,
    const float* __restrict__ opw, const float* __restrict__ scw,
    float* __restrict__ out)
{
    __shared__ float yt[64 * 97];
    __shared__ float hin[4][96];
    __shared__ float mu[64], isd[64];
    const int t = threadIdx.x;
    const int j = blockIdx.x & 255;
    const int b = blockIdx.x >> 8;
    const int l0 = j << 6;
    const int bk0 = b * 2, bk1 = b * 2 + 1;

    if (t < 96) {
        hin[0][t] = hinit[((size_t)bk0 * NCH + 2*j    ) * Cn + t];
        hin[1][t] = hinit[((size_t)bk0 * NCH + 2*j + 1) * Cn + t];
        hin[2][t] = hinit[((size_t)bk1 * NCH + 511-2*j) * Cn + t];
        hin[3][t] = hinit[((size_t)bk1 * NCH + 510-2*j) * Cn + t];
    }
    __syncthreads();

    const float* y0p = yloc + ((size_t)bk0 * Ln + l0) * Cn;
    const float* c0p = cpb  + ((size_t)bk0 * Ln + l0) * Cn;
    const float* ub  = u  + ((size_t)b * Ln + l0) * Cn;
    for (int jj = t; jj < 64 * Cn; jj += 256) {
        int c = jj % Cn, p = jj / Cn;
        int half = p >> 5;
        float y = fmaf(c0p[jj], hin[half][c], y0p[jj]);
        size_t g1 = ((size_t)bk1 * Ln + (Ln - 1 - l0 - p)) * Cn + c;
        y += fmaf(cpb[g1], hin[2 + half][c], yloc[g1]);
        y = fmaf(Ds[c] + Ds[Cn + c], ub[jj], y);
        yt[p * 97 + c] = y;
    }
    __syncthreads();

    if (t < 64) {
        float s = 0.f, ss = 0.f;
#pragma unroll
        for (int c = 0; c < Cn; ++c) { float v = yt[t * 97 + c]; s += v; ss += v * v; }
        float m = s * (1.f / Cn);
        float var = ss * (1.f / Cn) - m * m;
        mu[t] = m;
        isd[t] = rsqrtf(var + 1e-5f);
    }
    __syncthreads();

    const float* zb = zs + ((size_t)b * Ln + l0) * Cn;
    for (int jj = t; jj < 64 * Cn; jj += 256) {
        int c = jj % Cn, p = jj / Cn;
        float v = (yt[p * 97 + c] - mu[p]) * isd[p] * onw[c] + onb[c];
        yt[p * 97 + c] = v * zb[jj];
    }
    __syncthreads();

    for (int jj = t; jj < Cn * 64; jj += 256) {
        int pos = jj & 63, o = jj >> 6;
        const float* wr = opw + o * Cn;
        float acc = 0.f;
#pragma unroll
        for (int c = 0; c < Cn; ++c) acc = fmaf(wr[c], yt[pos * 97 + c], acc);
        out[((size_t)b * Cn + o) * Ln + l0 + pos] = acc * scw[o];
    }
}

// ---------------------------------------------------------------------------
extern "C" void kernel_launch(void* const* d_in, const int* in_sizes, int n_in,
                              void* d_out, int out_size, void* d_ws, size_t ws_size,
                              hipStream_t stream)
{
    const float* x     = (const float*)d_in[0];
    const float* ipw   = (const float*)d_in[1];
    const float* cw    = (const float*)d_in[2];
    const float* cb    = (const float*)d_in[3];
    const float* xpw   = (const float*)d_in[4];
    const float* dtw   = (const float*)d_in[5];
    const float* dtb   = (const float*)d_in[6];
    const float* Alogs = (const float*)d_in[7];
    const float* Ds    = (const float*)d_in[8];
    const float* onw   = (const float*)d_in[9];
    const float* onb   = (const float*)d_in[10];
    const float* opw   = (const float*)d_in[11];
    const float* scw   = (const float*)d_in[12];
    float* out = (float*)d_out;

    float* wsp = (float*)d_ws;
    size_t off = 0;
    // yloc (B*K*L*C) -- its first half doubles as xc (dead after k_conv)
    float* yloc = wsp + off;
    float* xc   = wsp + off; off += (size_t)Bn * Kn * Ln * Cn;    // 12.58M
    float* cpb  = wsp + off; off += (size_t)Bn * Kn * Ln * Cn;    // 12.58M
    float* zs   = wsp + off; off += (size_t)Bn * Ln * Cn;         // 6.29M
    float* u    = wsp + off; off += (size_t)Bn * Ln * Cn;         // 6.29M
    float* Pc    = wsp + off; off += (size_t)Bn * Kn * NCH * Cn;  // 0.39M
    float* Qc    = wsp + off; off += (size_t)Bn * Kn * NCH * Cn;
    float* hinit = wsp + off; off += (size_t)Bn * Kn * NCH * Cn;
    // total ~38.9M floats ~156 MB

    k_inproj<<<Bn * 256, 256, 0, stream>>>(x, ipw, xc, zs);
    k_conv  <<<(Bn * Ln * Cn) / 256, 256, 0, stream>>>(xc, cw, cb, u);
    k_fscan1<<<Bn * Kn * 256, 192, 0, stream>>>(u, xpw, dtw, dtb, Alogs,
                                                yloc, cpb, Pc, Qc);
    k_scan2 <<<24, 1024, 0, stream>>>(Pc, Qc, hinit);
    k_scan3 <<<Bn * 256, 256, 0, stream>>>(yloc, cpb, hinit, u, Ds, onw, onb,
                                           zs, opw, scw, out);
}

// Round 4
// 379.417 us; speedup vs baseline: 1.8969x; 1.1598x over previous
//
#include <hip/hip_runtime.h>
#include <math.h>

#define Bn 4
#define Cn 96
#define Hn 128
#define Wn 128
#define Ln (Hn*Wn)      // 16384
#define Kn 2
#define Rn 6
#define SC 16           // scan chunk length
#define NCH (Ln/SC)     // 1024 chunks per (b,k)

__device__ __forceinline__ float siluf(float x) { return x / (1.f + __expf(-x)); }
__device__ __forceinline__ float softplusf(float x) {
    return fmaxf(x, 0.f) + log1pf(__expf(-fabsf(x)));
}

// ---------------------------------------------------------------------------
// Kernel A: in_proj GEMM. x (B,C,L) -> xc (B,L,C), zs=silu(z) (B,L,C).
// block = 256 thr, tile 64 pos x 192 out, thread = 4 pos x 12 out.
// ---------------------------------------------------------------------------
__global__ __launch_bounds__(256, 4) void k_inproj(
    const float* __restrict__ x, const float* __restrict__ ipw,
    float* __restrict__ xc, float* __restrict__ zs)
{
    __shared__ float xls[32 * 64];       // [k][p]  8 KB
    __shared__ float wls[32 * 196];      // [k][o]  25 KB
    const int t  = threadIdx.x;
    const int b  = blockIdx.x >> 8;
    const int l0 = (blockIdx.x & 255) << 6;
    const int tx = t & 15;
    const int ty = t >> 4;

    float acc[12][4];
#pragma unroll
    for (int i = 0; i < 12; ++i)
#pragma unroll
        for (int j = 0; j < 4; ++j) acc[i][j] = 0.f;

    const float* xbase = x + (size_t)b * Cn * Ln + l0;

    for (int k0 = 0; k0 < Cn; k0 += 32) {
        if (k0) __syncthreads();
        {
            int idx = t;
#pragma unroll
            for (int q = 0; q < 2; ++q, idx += 256) {
                int k = idx >> 4, p4 = idx & 15;
                *(float4*)&xls[k * 64 + p4 * 4] =
                    *(const float4*)&xbase[(size_t)(k0 + k) * Ln + p4 * 4];
            }
        }
        for (int idx = t; idx < 32 * 192; idx += 256) {
            int o = idx % 192, k = idx / 192;
            wls[k * 196 + o] = ipw[o * Cn + k0 + k];
        }
        __syncthreads();

#pragma unroll 4
        for (int kk = 0; kk < 32; ++kk) {
            float4 xv = *(const float4*)&xls[kk * 64 + tx * 4];
            const float* wrow = &wls[kk * 196 + ty * 12];
            float4 w0 = *(const float4*)&wrow[0];
            float4 w1 = *(const float4*)&wrow[4];
            float4 w2 = *(const float4*)&wrow[8];
            float wv[12] = {w0.x,w0.y,w0.z,w0.w,w1.x,w1.y,w1.z,w1.w,w2.x,w2.y,w2.z,w2.w};
            float xa[4]  = {xv.x, xv.y, xv.z, xv.w};
#pragma unroll
            for (int i = 0; i < 12; ++i)
#pragma unroll
                for (int j = 0; j < 4; ++j)
                    acc[i][j] = fmaf(wv[i], xa[j], acc[i][j]);
        }
    }

    const size_t posbase = (size_t)b * Ln + l0 + tx * 4;
#pragma unroll
    for (int i = 0; i < 12; ++i) {
        const int o = ty * 12 + i;
        const bool isz = (o >= Cn);
        float* ob = isz ? (zs + posbase * Cn + (o - Cn)) : (xc + posbase * Cn + o);
#pragma unroll
        for (int j = 0; j < 4; ++j) {
            float v = acc[i][j];
            if (isz) v = siluf(v);
            ob[(size_t)j * Cn] = v;
        }
    }
}

// ---------------------------------------------------------------------------
// Kernel B: depthwise 3x3 conv (SAME) + bias + SiLU.  xc (B,L,C) -> u (B,L,C).
// ---------------------------------------------------------------------------
__global__ __launch_bounds__(256) void k_conv(
    const float* __restrict__ xc, const float* __restrict__ cw,
    const float* __restrict__ cb, float* __restrict__ u)
{
    const int e   = blockIdx.x * 256 + threadIdx.x;
    const int c   = e % Cn;
    const int pos = e / Cn;
    const int l   = pos % Ln;
    const int b   = pos / Ln;
    const int h   = l >> 7, w = l & 127;

    float acc = cb[c];
#pragma unroll
    for (int dh = -1; dh <= 1; ++dh) {
        int hh = h + dh;
        if (hh < 0 || hh >= Hn) continue;
#pragma unroll
        for (int dw = -1; dw <= 1; ++dw) {
            int ww = w + dw;
            if (ww < 0 || ww >= Wn) continue;
            acc = fmaf(cw[c*9 + (dh+1)*3 + (dw+1)],
                       xc[((size_t)b * Ln + (hh << 7) + ww) * Cn + c], acc);
        }
    }
    u[e] = siluf(acc);
}

// ---------------------------------------------------------------------------
// Kernel C: fused x_dbl + delta + local scan. 384 thr = 4 chunks x 96 channels,
// tile = 64 scan positions. k=1 results stored at SPATIAL indices so the
// epilogue reads forward. yloc = h_loc*C, cpb = cumP*C; (P,Q) carry per chunk.
// ---------------------------------------------------------------------------
__global__ __launch_bounds__(384) void k_fscan1(
    const float* __restrict__ u, const float* __restrict__ xpw,
    const float* __restrict__ dtw, const float* __restrict__ dtb,
    const float* __restrict__ Alogs,
    float* __restrict__ yloc, float* __restrict__ cpb,
    float* __restrict__ Pc, float* __restrict__ Qc)
{
    __shared__ float uls[64 * 100];  // [p][c] pad 100 (b128-aligned rows)
    __shared__ float xd[64 * 8];     // [p][d]
    const int t   = threadIdx.x;
    const int seg = blockIdx.x & 255;
    const int k   = (blockIdx.x >> 8) & 1;
    const int b   = blockIdx.x >> 9;
    const int bk  = b * Kn + k;
    const int l0  = seg << 6;        // scan-position base (64 positions)

    if (k == 0) {
        const float* up = u + ((size_t)b * Ln + l0) * Cn;
        for (int idx = t; idx < 64 * Cn; idx += 384) {
            int p = idx / Cn, c = idx % Cn;
            uls[p * 100 + c] = up[idx];
        }
    } else {
        const float* up = u + ((size_t)b * Ln + (Ln - 64 - l0)) * Cn;
        for (int idx = t; idx < 64 * Cn; idx += 384) {
            int p = 63 - idx / Cn, c = idx % Cn;
            uls[p * 100 + c] = up[idx];
        }
    }
    __syncthreads();

    // x_dbl: 8 projections x 64 positions, float4 dots
    for (int dp = t; dp < 512; dp += 384) {
        int d = dp & 7, p = dp >> 3;
        const float4* wr = (const float4*)(xpw + (k * 8 + d) * Cn);
        const float4* ur = (const float4*)&uls[p * 100];
        float acc = 0.f;
#pragma unroll
        for (int c4 = 0; c4 < 24; ++c4) {
            float4 w = wr[c4], v = ur[c4];
            acc = fmaf(w.x, v.x, acc); acc = fmaf(w.y, v.y, acc);
            acc = fmaf(w.z, v.z, acc); acc = fmaf(w.w, v.w, acc);
        }
        xd[p * 8 + d] = acc;
    }
    __syncthreads();

    const int c  = t % Cn;
    const int ci = t / Cn;           // chunk within tile: 0..3
    const int pbase = ci * SC;
    const float Av = -__expf(Alogs[k * Cn + c]);
    const float bias = dtb[k * Cn + c];
    float dtwr[Rn];
#pragma unroll
    for (int r = 0; r < Rn; ++r) dtwr[r] = dtw[(k * Cn + c) * Rn + r];

    float h = 0.f, cp = 1.f;
    const int sp0 = (k == 0) ? (l0 + pbase) : (Ln - 1 - l0 - pbase);
    const long long stride = (k == 0) ? (long long)Cn : -(long long)Cn;
    long long gb = ((long long)bk * Ln + sp0) * Cn + c;
    for (int i = 0; i < SC; ++i) {
        const float* xr = &xd[(pbase + i) * 8];
        float de = bias;
#pragma unroll
        for (int r = 0; r < Rn; ++r) de = fmaf(dtwr[r], xr[r], de);
        de = softplusf(de);
        float dA = __expf(de * Av);
        float xv = uls[(pbase + i) * 100 + c];
        h = fmaf(dA, h, de * xv * xr[6]);
        cp *= dA;
        yloc[gb] = h * xr[7];
        cpb [gb] = cp * xr[7];
        gb += stride;
    }
    const size_t cidx = ((size_t)bk * NCH + seg * 4 + ci) * Cn + c;
    Pc[cidx] = cp;
    Qc[cidx] = h;
}

// ---------------------------------------------------------------------------
// Kernel D: hierarchical carry scan. 768 series x 1024 chunks.
// Grid = 24 blocks (8 bk x 3 channel-slices of 32), block = 1024 thr (32c x 32g),
// group = 32 chunks: 32-step group carry, 32-step serial, 32-step replay.
// ---------------------------------------------------------------------------
__global__ __launch_bounds__(1024) void k_scan2(
    const float* __restrict__ Pc, const float* __restrict__ Qc,
    float* __restrict__ hinit)
{
    __shared__ float Pg[32][33], Qg[32][33], gini[32][33];
    const int bk    = blockIdx.x / 3;
    const int cbase = (blockIdx.x % 3) * 32;
    const int t = threadIdx.x;
    const int c = t & 31, g = t >> 5;

    const size_t base = ((size_t)bk * NCH + g * 32) * Cn + cbase + c;
    float P = 1.f, Q = 0.f;
    for (int j = 0; j < 32; ++j) {
        size_t idx = base + (size_t)j * Cn;
        float p_ = Pc[idx], q_ = Qc[idx];
        Q = fmaf(p_, Q, q_);
        P *= p_;
    }
    Pg[g][c] = P; Qg[g][c] = Q;
    __syncthreads();
    if (t < 32) {
        float h = 0.f;
        for (int gg = 0; gg < 32; ++gg) {
            gini[gg][t] = h;
            h = fmaf(Pg[gg][t], h, Qg[gg][t]);
        }
    }
    __syncthreads();
    float h = gini[g][c];
    for (int j = 0; j < 32; ++j) {
        size_t idx = base + (size_t)j * Cn;
        hinit[idx] = h;
        h = fmaf(Pc[idx], h, Qc[idx]);
    }
}

// ---------------------------------------------------------------------------
// Kernel E1: streaming correction + LayerNorm + gate. Writes g (aliases u).
// y = yloc0+cp0*h0 + yloc1+cp1*h1 + (D0+D1)*u; LN over C; g = LN(y)*zs.
// ---------------------------------------------------------------------------
__global__ __launch_bounds__(256) void k_scan3a(
    const float* __restrict__ yloc, const float* __restrict__ cpb,
    const float* __restrict__ hinit, const float* __restrict__ u,
    const float* __restrict__ Ds, const float* __restrict__ onw,
    const float* __restrict__ onb, const float* __restrict__ zs,
    float* __restrict__ g)
{
    __shared__ float yt[64 * 104];   // [p][c] pad 104
    __shared__ float hin[8][96];     // 0..3: k=0 quarters, 4..7: k=1 quarters
    __shared__ float dsum[96];
    __shared__ float mu[64], isd[64];
    const int t = threadIdx.x;
    const int j = blockIdx.x & 255;
    const int b = blockIdx.x >> 8;
    const int l0 = j << 6;
    const int bk0 = b * 2, bk1 = b * 2 + 1;

    for (int i = t; i < 8 * 96; i += 256) {
        int which = i / 96, c = i % 96;
        int chunk = (which < 4) ? (4 * j + which) : (1023 - 4 * j - (which - 4));
        int bkx   = (which < 4) ? bk0 : bk1;
        hin[which][c] = hinit[((size_t)bkx * NCH + chunk) * Cn + c];
    }
    if (t < 96) dsum[t] = Ds[t] + Ds[Cn + t];
    __syncthreads();

    const float4* y0p = (const float4*)(yloc + ((size_t)bk0 * Ln + l0) * Cn);
    const float4* c0p = (const float4*)(cpb  + ((size_t)bk0 * Ln + l0) * Cn);
    const float4* y1p = (const float4*)(yloc + ((size_t)bk1 * Ln + l0) * Cn);
    const float4* c1p = (const float4*)(cpb  + ((size_t)bk1 * Ln + l0) * Cn);
    const float4* up4 = (const float4*)(u + ((size_t)b * Ln + l0) * Cn);
    for (int e4 = t; e4 < 64 * 24; e4 += 256) {
        int p = e4 / 24, c4 = e4 % 24;
        int hb = p >> 4;
        float4 a0 = y0p[e4], s0 = c0p[e4], a1 = y1p[e4], s1 = c1p[e4], uv = up4[e4];
        float4 r;
        int c = c4 * 4;
        r.x = a0.x + s0.x * hin[hb][c+0] + a1.x + s1.x * hin[4+hb][c+0] + dsum[c+0] * uv.x;
        r.y = a0.y + s0.y * hin[hb][c+1] + a1.y + s1.y * hin[4+hb][c+1] + dsum[c+1] * uv.y;
        r.z = a0.z + s0.z * hin[hb][c+2] + a1.z + s1.z * hin[4+hb][c+2] + dsum[c+2] * uv.z;
        r.w = a0.w + s0.w * hin[hb][c+3] + a1.w + s1.w * hin[4+hb][c+3] + dsum[c+3] * uv.w;
        *(float4*)&yt[p * 104 + c] = r;
    }
    __syncthreads();

    // stats: 4 threads per position, 24 channels each, combine via shuffle
    {
        const int p = t >> 2, q = t & 3;
        const float4* row = (const float4*)&yt[p * 104 + q * 24];
        float s = 0.f, ss = 0.f;
#pragma unroll
        for (int i = 0; i < 6; ++i) {
            float4 v = row[i];
            s += v.x + v.y + v.z + v.w;
            ss += v.x*v.x + v.y*v.y + v.z*v.z + v.w*v.w;
        }
        s  += __shfl_xor(s, 1);  s  += __shfl_xor(s, 2);
        ss += __shfl_xor(ss, 1); ss += __shfl_xor(ss, 2);
        if (q == 0) {
            float m = s * (1.f / Cn);
            mu[p] = m;
            isd[p] = rsqrtf(ss * (1.f / Cn) - m * m + 1e-5f);
        }
    }
    __syncthreads();

    const float4* zp4 = (const float4*)(zs + ((size_t)b * Ln + l0) * Cn);
    const float4* w4  = (const float4*)onw;
    const float4* b4  = (const float4*)onb;
    float4* g4 = (float4*)(g + ((size_t)b * Ln + l0) * Cn);
    for (int e4 = t; e4 < 64 * 24; e4 += 256) {
        int p = e4 / 24, c4 = e4 % 24;
        float4 v = *(const float4*)&yt[p * 104 + c4 * 4];
        float4 wv = w4[c4], bv = b4[c4], zv = zp4[e4];
        float m = mu[p], is = isd[p];
        float4 r;
        r.x = ((v.x - m) * is * wv.x + bv.x) * zv.x;
        r.y = ((v.y - m) * is * wv.y + bv.y) * zv.y;
        r.z = ((v.z - m) * is * wv.z + bv.z) * zv.z;
        r.w = ((v.w - m) * is * wv.w + bv.w) * zv.w;
        g4[e4] = r;
    }
}

// ---------------------------------------------------------------------------
// Kernel E2: out_proj GEMM g (B,L,C) -> out (B,C,L), + scale_w.
// block = 256, tile 64 pos x 96 out, thread = 4 pos x 6 out, K chunked by 32.
// ---------------------------------------------------------------------------
__global__ __launch_bounds__(256) void k_scan3b(
    const float* __restrict__ g, const float* __restrict__ opw,
    const float* __restrict__ scw, float* __restrict__ out)
{
    __shared__ float gls[32 * 68];   // [k][p] pad 68
    __shared__ float wls[32 * 100];  // [k][o] pad 100
    const int t  = threadIdx.x;
    const int b  = blockIdx.x >> 8;
    const int l0 = (blockIdx.x & 255) << 6;
    const int tx = t & 15;           // 4 positions
    const int ty = t >> 4;           // 6 outputs

    float acc[6][4];
#pragma unroll
    for (int i = 0; i < 6; ++i)
#pragma unroll
        for (int j = 0; j < 4; ++j) acc[i][j] = 0.f;

    const float* gbase = g + ((size_t)b * Ln + l0) * Cn;

    for (int k0 = 0; k0 < Cn; k0 += 32) {
        if (k0) __syncthreads();
        // g tile: gls[k][p] = g[(l0+p)*Cn + k0+k]; lanes vary k fast (coalesced)
        for (int idx = t; idx < 2048; idx += 256) {
            int k = idx & 31, p = idx >> 5;
            gls[k * 68 + p] = gbase[(size_t)p * Cn + k0 + k];
        }
        // w tile: wls[k][o] = opw[o*Cn + k0+k]
        for (int idx = t; idx < 3072; idx += 256) {
            int k = idx & 31, o = idx >> 5;
            wls[k * 100 + o] = opw[o * Cn + k0 + k];
        }
        __syncthreads();

#pragma unroll 8
        for (int kk = 0; kk < 32; ++kk) {
            float4 gv = *(const float4*)&gls[kk * 68 + tx * 4];
            const float* wr = &wls[kk * 100 + ty * 6];
            float ga[4] = {gv.x, gv.y, gv.z, gv.w};
#pragma unroll
            for (int i = 0; i < 6; ++i) {
                float w = wr[i];
#pragma unroll
                for (int jq = 0; jq < 4; ++jq)
                    acc[i][jq] = fmaf(w, ga[jq], acc[i][jq]);
            }
        }
    }

#pragma unroll
    for (int i = 0; i < 6; ++i) {
        const int o = ty * 6 + i;
        const float sc = scw[o];
        float4 st = make_float4(acc[i][0]*sc, acc[i][1]*sc, acc[i][2]*sc, acc[i][3]*sc);
        *(float4*)&out[((size_t)b * Cn + o) * Ln + l0 + tx * 4] = st;
    }
}

// ---------------------------------------------------------------------------
extern "C" void kernel_launch(void* const* d_in, const int* in_sizes, int n_in,
                              void* d_out, int out_size, void* d_ws, size_t ws_size,
                              hipStream_t stream)
{
    const float* x     = (const float*)d_in[0];
    const float* ipw   = (const float*)d_in[1];
    const float* cw    = (const float*)d_in[2];
    const float* cb    = (const float*)d_in[3];
    const float* xpw   = (const float*)d_in[4];
    const float* dtw   = (const float*)d_in[5];
    const float* dtb   = (const float*)d_in[6];
    const float* Alogs = (const float*)d_in[7];
    const float* Ds    = (const float*)d_in[8];
    const float* onw   = (const float*)d_in[9];
    const float* onb   = (const float*)d_in[10];
    const float* opw   = (const float*)d_in[11];
    const float* scw   = (const float*)d_in[12];
    float* out = (float*)d_out;

    float* wsp = (float*)d_ws;
    size_t off = 0;
    // yloc (B*K*L*C); first half doubles as xc (dead after k_conv)
    float* yloc = wsp + off;
    float* xc   = wsp + off; off += (size_t)Bn * Kn * Ln * Cn;    // 12.58M
    float* cpb  = wsp + off; off += (size_t)Bn * Kn * Ln * Cn;    // 12.58M
    float* zs   = wsp + off; off += (size_t)Bn * Ln * Cn;         // 6.29M
    // u (conv->scan3a); g aliases u (same-index read-before-write in scan3a)
    float* u    = wsp + off;
    float* g    = wsp + off; off += (size_t)Bn * Ln * Cn;         // 6.29M
    float* Pc    = wsp + off; off += (size_t)Bn * Kn * NCH * Cn;  // 0.79M
    float* Qc    = wsp + off; off += (size_t)Bn * Kn * NCH * Cn;
    float* hinit = wsp + off; off += (size_t)Bn * Kn * NCH * Cn;
    // total ~40.1M floats ~160 MB? no: 12.58*2+6.29*2+0.79*3 = 40.1M -> 156 MB w/ NCH*Cn=98304*... (0.393M ea)

    k_inproj<<<Bn * 256, 256, 0, stream>>>(x, ipw, xc, zs);
    k_conv  <<<(Bn * Ln * Cn) / 256, 256, 0, stream>>>(xc, cw, cb, u);
    k_fscan1<<<Bn * Kn * 256, 384, 0, stream>>>(u, xpw, dtw, dtb, Alogs,
                                                yloc, cpb, Pc, Qc);
    k_scan2 <<<24, 1024, 0, stream>>>(Pc, Qc, hinit);
    k_scan3a<<<Bn * 256, 256, 0, stream>>>(yloc, cpb, hinit, u, Ds, onw, onb, zs, g);
    k_scan3b<<<Bn * 256, 256, 0, stream>>>(g, opw, scw, out);
}

// Round 5
// 357.979 us; speedup vs baseline: 2.0105x; 1.0599x over previous
//
#include <hip/hip_runtime.h>
#include <math.h>

#define Bn 4
#define Cn 96
#define Hn 128
#define Wn 128
#define Ln (Hn*Wn)      // 16384
#define Kn 2
#define Rn 6
#define SC 16           // scan chunk length
#define NCH (Ln/SC)     // 1024 chunks per (b,k)

__device__ __forceinline__ float siluf(float x) { return x / (1.f + __expf(-x)); }
__device__ __forceinline__ float softplusf(float x) {
    return fmaxf(x, 0.f) + log1pf(__expf(-fabsf(x)));
}

// ---------------------------------------------------------------------------
// Kernel A: in_proj GEMM. x (B,C,L) -> xc (B,L,C), zs=silu(z) (B,L,C).
// block = 256 thr, tile 64 pos x 192 out, thread = 4 pos x 12 out.
// Epilogue stages the output tile in LDS (reusing the K-loop buffers) so all
// global stores are coalesced float4 — without this, scalar lane-strided
// stores caused 4.6x HBM write amplification (220 MB vs 48 MB ideal).
// ---------------------------------------------------------------------------
__global__ __launch_bounds__(256, 4) void k_inproj(
    const float* __restrict__ x, const float* __restrict__ ipw,
    float* __restrict__ xc, float* __restrict__ zs)
{
    __shared__ float smem[2048 + 6272];  // xls(32x64) + wls(32x196) = 33.3 KB
    float* xls = smem;                   // [k][p]
    float* wls = smem + 2048;            // [k][o] pad 196
    float* stage = smem;                 // reused after K loop: [p][c] pad 100

    const int t  = threadIdx.x;
    const int b  = blockIdx.x >> 8;
    const int l0 = (blockIdx.x & 255) << 6;
    const int tx = t & 15;
    const int ty = t >> 4;

    float acc[12][4];
#pragma unroll
    for (int i = 0; i < 12; ++i)
#pragma unroll
        for (int j = 0; j < 4; ++j) acc[i][j] = 0.f;

    const float* xbase = x + (size_t)b * Cn * Ln + l0;

    for (int k0 = 0; k0 < Cn; k0 += 32) {
        if (k0) __syncthreads();
        {
            int idx = t;
#pragma unroll
            for (int q = 0; q < 2; ++q, idx += 256) {
                int k = idx >> 4, p4 = idx & 15;
                *(float4*)&xls[k * 64 + p4 * 4] =
                    *(const float4*)&xbase[(size_t)(k0 + k) * Ln + p4 * 4];
            }
        }
        for (int idx = t; idx < 32 * 192; idx += 256) {
            int o = idx % 192, k = idx / 192;
            wls[k * 196 + o] = ipw[o * Cn + k0 + k];
        }
        __syncthreads();

#pragma unroll 4
        for (int kk = 0; kk < 32; ++kk) {
            float4 xv = *(const float4*)&xls[kk * 64 + tx * 4];
            const float* wrow = &wls[kk * 196 + ty * 12];
            float4 w0 = *(const float4*)&wrow[0];
            float4 w1 = *(const float4*)&wrow[4];
            float4 w2 = *(const float4*)&wrow[8];
            float wv[12] = {w0.x,w0.y,w0.z,w0.w,w1.x,w1.y,w1.z,w1.w,w2.x,w2.y,w2.z,w2.w};
            float xa[4]  = {xv.x, xv.y, xv.z, xv.w};
#pragma unroll
            for (int i = 0; i < 12; ++i)
#pragma unroll
                for (int j = 0; j < 4; ++j)
                    acc[i][j] = fmaf(wv[i], xa[j], acc[i][j]);
        }
    }

    // ---- epilogue: LDS-staged coalesced stores ----
    __syncthreads();
    // pass 1: xc rows (outputs 0..95 -> ty < 8)
    if (ty < 8) {
#pragma unroll
        for (int j = 0; j < 4; ++j)
#pragma unroll
            for (int i = 0; i < 12; ++i)
                stage[(tx * 4 + j) * 100 + ty * 12 + i] = acc[i][j];
    }
    __syncthreads();
    {
        float4* dst = (float4*)(xc + ((size_t)b * Ln + l0) * Cn);
        for (int idx = t; idx < 1536; idx += 256) {
            int p = idx / 24, c4 = idx % 24;
            dst[idx] = *(const float4*)&stage[p * 100 + c4 * 4];
        }
    }
    __syncthreads();
    // pass 2: zs rows (outputs 96..191 -> ty >= 8), silu applied
    if (ty >= 8) {
#pragma unroll
        for (int j = 0; j < 4; ++j)
#pragma unroll
            for (int i = 0; i < 12; ++i)
                stage[(tx * 4 + j) * 100 + (ty - 8) * 12 + i] = siluf(acc[i][j]);
    }
    __syncthreads();
    {
        float4* dst = (float4*)(zs + ((size_t)b * Ln + l0) * Cn);
        for (int idx = t; idx < 1536; idx += 256) {
            int p = idx / 24, c4 = idx % 24;
            dst[idx] = *(const float4*)&stage[p * 100 + c4 * 4];
        }
    }
}

// ---------------------------------------------------------------------------
// Kernel B: depthwise 3x3 conv (SAME) + bias + SiLU.  xc (B,L,C) -> u (B,L,C).
// ---------------------------------------------------------------------------
__global__ __launch_bounds__(256) void k_conv(
    const float* __restrict__ xc, const float* __restrict__ cw,
    const float* __restrict__ cb, float* __restrict__ u)
{
    const int e   = blockIdx.x * 256 + threadIdx.x;
    const int c   = e % Cn;
    const int pos = e / Cn;
    const int l   = pos % Ln;
    const int b   = pos / Ln;
    const int h   = l >> 7, w = l & 127;

    float acc = cb[c];
#pragma unroll
    for (int dh = -1; dh <= 1; ++dh) {
        int hh = h + dh;
        if (hh < 0 || hh >= Hn) continue;
#pragma unroll
        for (int dw = -1; dw <= 1; ++dw) {
            int ww = w + dw;
            if (ww < 0 || ww >= Wn) continue;
            acc = fmaf(cw[c*9 + (dh+1)*3 + (dw+1)],
                       xc[((size_t)b * Ln + (hh << 7) + ww) * Cn + c], acc);
        }
    }
    u[e] = siluf(acc);
}

// ---------------------------------------------------------------------------
// Kernel C: fused x_dbl + delta + local scan. 384 thr = 4 chunks x 96 channels,
// tile = 64 scan positions. k=1 results stored at SPATIAL indices so the
// epilogue reads forward. yloc = h_loc*C, cpb = cumP*C; (P,Q) carry per chunk.
// ---------------------------------------------------------------------------
__global__ __launch_bounds__(384) void k_fscan1(
    const float* __restrict__ u, const float* __restrict__ xpw,
    const float* __restrict__ dtw, const float* __restrict__ dtb,
    const float* __restrict__ Alogs,
    float* __restrict__ yloc, float* __restrict__ cpb,
    float* __restrict__ Pc, float* __restrict__ Qc)
{
    __shared__ float uls[64 * 100];  // [p][c] pad 100 (b128-aligned rows)
    __shared__ float xd[64 * 8];     // [p][d]
    const int t   = threadIdx.x;
    const int seg = blockIdx.x & 255;
    const int k   = (blockIdx.x >> 8) & 1;
    const int b   = blockIdx.x >> 9;
    const int bk  = b * Kn + k;
    const int l0  = seg << 6;        // scan-position base (64 positions)

    if (k == 0) {
        const float* up = u + ((size_t)b * Ln + l0) * Cn;
        for (int idx = t; idx < 64 * Cn; idx += 384) {
            int p = idx / Cn, c = idx % Cn;
            uls[p * 100 + c] = up[idx];
        }
    } else {
        const float* up = u + ((size_t)b * Ln + (Ln - 64 - l0)) * Cn;
        for (int idx = t; idx < 64 * Cn; idx += 384) {
            int p = 63 - idx / Cn, c = idx % Cn;
            uls[p * 100 + c] = up[idx];
        }
    }
    __syncthreads();

    // x_dbl: 8 projections x 64 positions, float4 dots
    for (int dp = t; dp < 512; dp += 384) {
        int d = dp & 7, p = dp >> 3;
        const float4* wr = (const float4*)(xpw + (k * 8 + d) * Cn);
        const float4* ur = (const float4*)&uls[p * 100];
        float acc = 0.f;
#pragma unroll
        for (int c4 = 0; c4 < 24; ++c4) {
            float4 w = wr[c4], v = ur[c4];
            acc = fmaf(w.x, v.x, acc); acc = fmaf(w.y, v.y, acc);
            acc = fmaf(w.z, v.z, acc); acc = fmaf(w.w, v.w, acc);
        }
        xd[p * 8 + d] = acc;
    }
    __syncthreads();

    const int c  = t % Cn;
    const int ci = t / Cn;           // chunk within tile: 0..3
    const int pbase = ci * SC;
    const float Av = -__expf(Alogs[k * Cn + c]);
    const float bias = dtb[k * Cn + c];
    float dtwr[Rn];
#pragma unroll
    for (int r = 0; r < Rn; ++r) dtwr[r] = dtw[(k * Cn + c) * Rn + r];

    float h = 0.f, cp = 1.f;
    const int sp0 = (k == 0) ? (l0 + pbase) : (Ln - 1 - l0 - pbase);
    const long long stride = (k == 0) ? (long long)Cn : -(long long)Cn;
    long long gb = ((long long)bk * Ln + sp0) * Cn + c;
    for (int i = 0; i < SC; ++i) {
        const float* xr = &xd[(pbase + i) * 8];
        float de = bias;
#pragma unroll
        for (int r = 0; r < Rn; ++r) de = fmaf(dtwr[r], xr[r], de);
        de = softplusf(de);
        float dA = __expf(de * Av);
        float xv = uls[(pbase + i) * 100 + c];
        h = fmaf(dA, h, de * xv * xr[6]);
        cp *= dA;
        yloc[gb] = h * xr[7];
        cpb [gb] = cp * xr[7];
        gb += stride;
    }
    const size_t cidx = ((size_t)bk * NCH + seg * 4 + ci) * Cn + c;
    Pc[cidx] = cp;
    Qc[cidx] = h;
}

// ---------------------------------------------------------------------------
// Kernel D: hierarchical carry scan. 768 series x 1024 chunks.
// Grid = 24 blocks (8 bk x 3 channel-slices of 32), block = 1024 thr (32c x 32g),
// group = 32 chunks: 32-step group carry, 32-step serial, 32-step replay.
// ---------------------------------------------------------------------------
__global__ __launch_bounds__(1024) void k_scan2(
    const float* __restrict__ Pc, const float* __restrict__ Qc,
    float* __restrict__ hinit)
{
    __shared__ float Pg[32][33], Qg[32][33], gini[32][33];
    const int bk    = blockIdx.x / 3;
    const int cbase = (blockIdx.x % 3) * 32;
    const int t = threadIdx.x;
    const int c = t & 31, g = t >> 5;

    const size_t base = ((size_t)bk * NCH + g * 32) * Cn + cbase + c;
    float P = 1.f, Q = 0.f;
    for (int j = 0; j < 32; ++j) {
        size_t idx = base + (size_t)j * Cn;
        float p_ = Pc[idx], q_ = Qc[idx];
        Q = fmaf(p_, Q, q_);
        P *= p_;
    }
    Pg[g][c] = P; Qg[g][c] = Q;
    __syncthreads();
    if (t < 32) {
        float h = 0.f;
        for (int gg = 0; gg < 32; ++gg) {
            gini[gg][t] = h;
            h = fmaf(Pg[gg][t], h, Qg[gg][t]);
        }
    }
    __syncthreads();
    float h = gini[g][c];
    for (int j = 0; j < 32; ++j) {
        size_t idx = base + (size_t)j * Cn;
        hinit[idx] = h;
        h = fmaf(Pc[idx], h, Qc[idx]);
    }
}

// ---------------------------------------------------------------------------
// Kernel E1: streaming correction + LayerNorm + gate. Writes g (aliases u).
// y = yloc0+cp0*h0 + yloc1+cp1*h1 + (D0+D1)*u; LN over C; g = LN(y)*zs.
// ---------------------------------------------------------------------------
__global__ __launch_bounds__(256) void k_scan3a(
    const float* __restrict__ yloc, const float* __restrict__ cpb,
    const float* __restrict__ hinit, const float* __restrict__ u,
    const float* __restrict__ Ds, const float* __restrict__ onw,
    const float* __restrict__ onb, const float* __restrict__ zs,
    float* __restrict__ g)
{
    __shared__ float yt[64 * 104];   // [p][c] pad 104
    __shared__ float hin[8][96];     // 0..3: k=0 quarters, 4..7: k=1 quarters
    __shared__ float dsum[96];
    __shared__ float mu[64], isd[64];
    const int t = threadIdx.x;
    const int j = blockIdx.x & 255;
    const int b = blockIdx.x >> 8;
    const int l0 = j << 6;
    const int bk0 = b * 2, bk1 = b * 2 + 1;

    for (int i = t; i < 8 * 96; i += 256) {
        int which = i / 96, c = i % 96;
        int chunk = (which < 4) ? (4 * j + which) : (1023 - 4 * j - (which - 4));
        int bkx   = (which < 4) ? bk0 : bk1;
        hin[which][c] = hinit[((size_t)bkx * NCH + chunk) * Cn + c];
    }
    if (t < 96) dsum[t] = Ds[t] + Ds[Cn + t];
    __syncthreads();

    const float4* y0p = (const float4*)(yloc + ((size_t)bk0 * Ln + l0) * Cn);
    const float4* c0p = (const float4*)(cpb  + ((size_t)bk0 * Ln + l0) * Cn);
    const float4* y1p = (const float4*)(yloc + ((size_t)bk1 * Ln + l0) * Cn);
    const float4* c1p = (const float4*)(cpb  + ((size_t)bk1 * Ln + l0) * Cn);
    const float4* up4 = (const float4*)(u + ((size_t)b * Ln + l0) * Cn);
    for (int e4 = t; e4 < 64 * 24; e4 += 256) {
        int p = e4 / 24, c4 = e4 % 24;
        int hb = p >> 4;
        float4 a0 = y0p[e4], s0 = c0p[e4], a1 = y1p[e4], s1 = c1p[e4], uv = up4[e4];
        float4 r;
        int c = c4 * 4;
        r.x = a0.x + s0.x * hin[hb][c+0] + a1.x + s1.x * hin[4+hb][c+0] + dsum[c+0] * uv.x;
        r.y = a0.y + s0.y * hin[hb][c+1] + a1.y + s1.y * hin[4+hb][c+1] + dsum[c+1] * uv.y;
        r.z = a0.z + s0.z * hin[hb][c+2] + a1.z + s1.z * hin[4+hb][c+2] + dsum[c+2] * uv.z;
        r.w = a0.w + s0.w * hin[hb][c+3] + a1.w + s1.w * hin[4+hb][c+3] + dsum[c+3] * uv.w;
        *(float4*)&yt[p * 104 + c] = r;
    }
    __syncthreads();

    // stats: 4 threads per position, 24 channels each, combine via shuffle
    {
        const int p = t >> 2, q = t & 3;
        const float4* row = (const float4*)&yt[p * 104 + q * 24];
        float s = 0.f, ss = 0.f;
#pragma unroll
        for (int i = 0; i < 6; ++i) {
            float4 v = row[i];
            s += v.x + v.y + v.z + v.w;
            ss += v.x*v.x + v.y*v.y + v.z*v.z + v.w*v.w;
        }
        s  += __shfl_xor(s, 1);  s  += __shfl_xor(s, 2);
        ss += __shfl_xor(ss, 1); ss += __shfl_xor(ss, 2);
        if (q == 0) {
            float m = s * (1.f / Cn);
            mu[p] = m;
            isd[p] = rsqrtf(ss * (1.f / Cn) - m * m + 1e-5f);
        }
    }
    __syncthreads();

    const float4* zp4 = (const float4*)(zs + ((size_t)b * Ln + l0) * Cn);
    const float4* w4  = (const float4*)onw;
    const float4* b4  = (const float4*)onb;
    float4* g4 = (float4*)(g + ((size_t)b * Ln + l0) * Cn);
    for (int e4 = t; e4 < 64 * 24; e4 += 256) {
        int p = e4 / 24, c4 = e4 % 24;
        float4 v = *(const float4*)&yt[p * 104 + c4 * 4];
        float4 wv = w4[c4], bv = b4[c4], zv = zp4[e4];
        float m = mu[p], is = isd[p];
        float4 r;
        r.x = ((v.x - m) * is * wv.x + bv.x) * zv.x;
        r.y = ((v.y - m) * is * wv.y + bv.y) * zv.y;
        r.z = ((v.z - m) * is * wv.z + bv.z) * zv.z;
        r.w = ((v.w - m) * is * wv.w + bv.w) * zv.w;
        g4[e4] = r;
    }
}

// ---------------------------------------------------------------------------
// Kernel E2: out_proj GEMM g (B,L,C) -> out (B,C,L), + scale_w.
// block = 256, tile 64 pos x 96 out, thread = 4 pos x 6 out, K chunked by 32.
// ---------------------------------------------------------------------------
__global__ __launch_bounds__(256) void k_scan3b(
    const float* __restrict__ g, const float* __restrict__ opw,
    const float* __restrict__ scw, float* __restrict__ out)
{
    __shared__ float gls[32 * 68];   // [k][p] pad 68
    __shared__ float wls[32 * 100];  // [k][o] pad 100
    const int t  = threadIdx.x;
    const int b  = blockIdx.x >> 8;
    const int l0 = (blockIdx.x & 255) << 6;
    const int tx = t & 15;           // 4 positions
    const int ty = t >> 4;           // 6 outputs

    float acc[6][4];
#pragma unroll
    for (int i = 0; i < 6; ++i)
#pragma unroll
        for (int j = 0; j < 4; ++j) acc[i][j] = 0.f;

    const float* gbase = g + ((size_t)b * Ln + l0) * Cn;

    for (int k0 = 0; k0 < Cn; k0 += 32) {
        if (k0) __syncthreads();
        // g tile: gls[k][p] = g[(l0+p)*Cn + k0+k]; lanes vary k fast (coalesced)
        for (int idx = t; idx < 2048; idx += 256) {
            int k = idx & 31, p = idx >> 5;
            gls[k * 68 + p] = gbase[(size_t)p * Cn + k0 + k];
        }
        // w tile: wls[k][o] = opw[o*Cn + k0+k]
        for (int idx = t; idx < 3072; idx += 256) {
            int k = idx & 31, o = idx >> 5;
            wls[k * 100 + o] = opw[o * Cn + k0 + k];
        }
        __syncthreads();

#pragma unroll 8
        for (int kk = 0; kk < 32; ++kk) {
            float4 gv = *(const float4*)&gls[kk * 68 + tx * 4];
            const float* wr = &wls[kk * 100 + ty * 6];
            float ga[4] = {gv.x, gv.y, gv.z, gv.w};
#pragma unroll
            for (int i = 0; i < 6; ++i) {
                float w = wr[i];
#pragma unroll
                for (int jq = 0; jq < 4; ++jq)
                    acc[i][jq] = fmaf(w, ga[jq], acc[i][jq]);
            }
        }
    }

#pragma unroll
    for (int i = 0; i < 6; ++i) {
        const int o = ty * 6 + i;
        const float sc = scw[o];
        float4 st = make_float4(acc[i][0]*sc, acc[i][1]*sc, acc[i][2]*sc, acc[i][3]*sc);
        *(float4*)&out[((size_t)b * Cn + o) * Ln + l0 + tx * 4] = st;
    }
}

// ---------------------------------------------------------------------------
extern "C" void kernel_launch(void* const* d_in, const int* in_sizes, int n_in,
                              void* d_out, int out_size, void* d_ws, size_t ws_size,
                              hipStream_t stream)
{
    const float* x     = (const float*)d_in[0];
    const float* ipw   = (const float*)d_in[1];
    const float* cw    = (const float*)d_in[2];
    const float* cb    = (const float*)d_in[3];
    const float* xpw   = (const float*)d_in[4];
    const float* dtw   = (const float*)d_in[5];
    const float* dtb   = (const float*)d_in[6];
    const float* Alogs = (const float*)d_in[7];
    const float* Ds    = (const float*)d_in[8];
    const float* onw   = (const float*)d_in[9];
    const float* onb   = (const float*)d_in[10];
    const float* opw   = (const float*)d_in[11];
    const float* scw   = (const float*)d_in[12];
    float* out = (float*)d_out;

    float* wsp = (float*)d_ws;
    size_t off = 0;
    // yloc (B*K*L*C); first half doubles as xc (dead after k_conv)
    float* yloc = wsp + off;
    float* xc   = wsp + off; off += (size_t)Bn * Kn * Ln * Cn;    // 12.58M
    float* cpb  = wsp + off; off += (size_t)Bn * Kn * Ln * Cn;    // 12.58M
    float* zs   = wsp + off; off += (size_t)Bn * Ln * Cn;         // 6.29M
    // u (conv->scan3a); g aliases u (same-index read-before-write in scan3a)
    float* u    = wsp + off;
    float* g    = wsp + off; off += (size_t)Bn * Ln * Cn;         // 6.29M
    float* Pc    = wsp + off; off += (size_t)Bn * Kn * NCH * Cn;  // 0.79M
    float* Qc    = wsp + off; off += (size_t)Bn * Kn * NCH * Cn;
    float* hinit = wsp + off; off += (size_t)Bn * Kn * NCH * Cn;

    k_inproj<<<Bn * 256, 256, 0, stream>>>(x, ipw, xc, zs);
    k_conv  <<<(Bn * Ln * Cn) / 256, 256, 0, stream>>>(xc, cw, cb, u);
    k_fscan1<<<Bn * Kn * 256, 384, 0, stream>>>(u, xpw, dtw, dtb, Alogs,
                                                yloc, cpb, Pc, Qc);
    k_scan2 <<<24, 1024, 0, stream>>>(Pc, Qc, hinit);
    k_scan3a<<<Bn * 256, 256, 0, stream>>>(yloc, cpb, hinit, u, Ds, onw, onb, zs, g);
    k_scan3b<<<Bn * 256, 256, 0, stream>>>(g, opw, scw, out);
}